// Round 5
// baseline (1330.833 us; speedup 1.0000x reference)
//
#include <hip/hip_runtime.h>

// ---------------------------------------------------------------------------
// ImprovedVietnameseVQAModel: MHA + LN + modality-routed expert FFN + LN
// B=8 S=2048 H=1024 NH=8 DH=128 FF=4096, fp32 in/out, bf16 MFMA compute.
// R7: gemm_bt counted-vmcnt pipeline (T4). R6's __syncthreads per step was
//     drain-0 (vmcnt(0) waits on the just-issued prefetch too) -> step time
//     pinned at full load latency. Now: STAGE(next) -> s_waitcnt vmcnt(4)
//     (prev tile's loads only; new 4 stay in flight across the barrier) ->
//     s_barrier -> ds_read+MFMA -> s_barrier. Keeps R6 coalesced staging +
//     chunk swizzle. Flash_attn unchanged.
// ---------------------------------------------------------------------------

#define B_ 8
#define S_ 2048
#define H_ 1024
#define NH_ 8
#define DH_ 128
#define FF_ 4096
#define TOK (B_ * S_)         // 16384
#define H3 (3 * H_)           // 3072

using short8 = __attribute__((ext_vector_type(8))) short;
using f32x4  = __attribute__((ext_vector_type(4))) float;

__device__ __forceinline__ short f2b(float f) {
  union { float f; unsigned u; } x; x.f = f;
  unsigned r = x.u + 0x7fffu + ((x.u >> 16) & 1u);
  return (short)(r >> 16);
}

__device__ __forceinline__ float b2f(short s) {
  union { unsigned u; float f; } x;
  x.u = ((unsigned)(unsigned short)s) << 16;
  return x.f;
}

// gelu(v) = v * sigmoid(1.5957691216*(v + 0.044715 v^3)); |err| ~1e-3 << bf16
__device__ __forceinline__ float gelu_fast(float v) {
  float u = 1.5957691216057308f * (v + 0.044715f * v * v * v);
  return v * __builtin_amdgcn_rcpf(1.0f + __expf(-u));
}

__device__ __forceinline__ void load16_lds(const void* g, void* l) {
  __builtin_amdgcn_global_load_lds(
      (__attribute__((address_space(1))) void*)(g),
      (__attribute__((address_space(3))) void*)(l), 16, 0, 0);
}

#define MFMA16(a, b, c) __builtin_amdgcn_mfma_f32_16x16x32_bf16((a), (b), (c), 0, 0, 0)

struct Ptr3 { const float* p[3]; };

// ---------------------------------------------------------------------------
__global__ __launch_bounds__(256) void cvt_bf16(const float* __restrict__ in,
                                                short* __restrict__ out, int n4) {
  int i = blockIdx.x * 256 + threadIdx.x;
  if (i >= n4) return;
  float4 v = *(const float4*)(in + (size_t)i * 4);
  short4 s;
  s.x = f2b(v.x); s.y = f2b(v.y); s.z = f2b(v.z); s.w = f2b(v.w);
  *(short4*)(out + (size_t)i * 4) = s;
}

// ---------------------------------------------------------------------------
__global__ __launch_bounds__(256) void transpose_cvt(const float* __restrict__ in,
                                                     short* __restrict__ out,
                                                     int R, int C) {
  __shared__ float t[32][33];
  int c0 = blockIdx.x * 32, r0 = blockIdx.y * 32;
  int tx = threadIdx.x, ty = threadIdx.y;
#pragma unroll
  for (int i = 0; i < 4; ++i)
    t[ty + i * 8][tx] = in[(size_t)(r0 + ty + i * 8) * C + c0 + tx];
  __syncthreads();
#pragma unroll
  for (int i = 0; i < 4; ++i)
    out[(size_t)(c0 + ty + i * 8) * R + r0 + tx] = f2b(t[tx][ty + i * 8]);
}

// ---------------------------------------------------------------------------
// V pre-transpose: QKV[b,key, 2H + h*128 + d] -> VT[(b*NH+h)*128 + d][key]
// so flash_attn can stage V tiles with coalesced global_load_lds.
// ---------------------------------------------------------------------------
__global__ __launch_bounds__(256) void transpose_v(const short* __restrict__ qkv,
                                                   short* __restrict__ vt) {
  __shared__ short t[32][33];
  int key0 = blockIdx.x * 32, d0 = blockIdx.y * 32, bh = blockIdx.z;
  int b = bh >> 3, h = bh & 7;
  int tx = threadIdx.x, ty = threadIdx.y;
  const short* src = qkv + (size_t)(b * S_ + key0) * H3 + 2 * H_ + h * DH_ + d0;
#pragma unroll
  for (int i = 0; i < 4; ++i)
    t[ty + i * 8][tx] = src[(size_t)(ty + i * 8) * H3 + tx];   // t[key][d]
  __syncthreads();
  short* dst = vt + ((size_t)bh * DH_ + d0) * S_ + key0;
#pragma unroll
  for (int i = 0; i < 4; ++i)
    dst[(size_t)(ty + i * 8) * S_ + tx] = t[tx][ty + i * 8];   // VT[d][key]
}

// ---------------------------------------------------------------------------
// Generic bf16 GEMM:  C[M,N] = A[M,K] @ Bt[N,K]^T (+bias, epilogue)
// 128x128 tile, BK=32, 256 thr = 4 waves each 64x64 (4x4 MFMA 16x16x32).
// Staging: row = tid>>2, ch = tid&3 -> 64B-contiguous per row (coalesced).
// LDS [row][ch] with stored chunk = global chunk ^ s(row), s=(row^(row>>2))&3.
// Pipeline (T4): STAGE(next) -> vmcnt(4) [prev tile only] -> s_barrier ->
// ds_read+MFMA -> s_barrier. Prefetch stays in flight across the barrier.
// MFMA operands swapped: acc[i][j] holds m = wm+i*16+(lane&15),
// n = wn+j*16+(lane>>4)*4+r  -> 4 consecutive cols per lane -> vector stores.
// EPI: 0 = bf16 C (+bias), 1 = bf16 C (+bias, fast GELU), 2 = fp32 C (+bias)
// ---------------------------------------------------------------------------
template <int EPI, bool IA, bool IC, bool GUARD>
__global__ __launch_bounds__(256) void gemm_bt(const short* __restrict__ A,
                                               const short* __restrict__ Bt,
                                               void* __restrict__ Cp, Ptr3 bias3,
                                               int N, int K,
                                               const int* __restrict__ perm,
                                               const int* __restrict__ meta) {
  const int m0 = blockIdx.x * 128, n0 = blockIdx.y * 128, e = blockIdx.z;
  int rlo = 0, rhi = 0x7fffffff;
  if (GUARD) {
    rlo = meta[3 + e];
    rhi = rlo + meta[e];
    if (m0 >= rhi || m0 + 128 <= rlo) return;
  }
  const short* Bte = Bt + (size_t)e * N * K;
  const float* bias = bias3.p[e];

  __shared__ alignas(16) short As0[4096];
  __shared__ alignas(16) short As1[4096];
  __shared__ alignas(16) short Bs0[4096];
  __shared__ alignas(16) short Bs1[4096];
  __shared__ int rmap[128];

  const int tid = threadIdx.x;
  const int lane = tid & 63, wave = tid >> 6;
  const int ln15 = lane & 15, l4 = lane >> 4;
  const int wm = (wave & 1) * 64, wn = (wave >> 1) * 64;

  if (IC && tid < 128) rmap[tid] = perm[m0 + tid];

  // staging geometry: thread -> (srow, sch); rows srow and 64+srow.
  const int srow = tid >> 2, sch = tid & 3;
  const int s0 = (srow ^ (srow >> 2)) & 3;      // same for row 64+srow
  int ar0 = m0 + srow, ar1 = m0 + 64 + srow;
  if (IA) { ar0 = perm[ar0]; ar1 = perm[ar1]; }
  const short* gaA0 = A + (size_t)ar0 * K + (sch ^ s0) * 8;
  const short* gaA1 = A + (size_t)ar1 * K + (sch ^ s0) * 8;
  const short* gbB0 = Bte + (size_t)(n0 + srow) * K + (sch ^ s0) * 8;
  const short* gbB1 = Bte + (size_t)(n0 + 64 + srow) * K + (sch ^ s0) * 8;
  const int d0 = (srow * 4 + sch) * 8;          // LDS dst (shorts), rows 0..63
  const int d1 = ((64 + srow) * 4 + sch) * 8;   // rows 64..127

  const f32x4 fz = {0.f, 0.f, 0.f, 0.f};
  f32x4 acc[4][4];
#pragma unroll
  for (int i = 0; i < 4; ++i)
#pragma unroll
    for (int j = 0; j < 4; ++j) acc[i][j] = fz;

#define STAGE(AsP, BsP, k0)                      \
  do {                                           \
    load16_lds(gaA0 + (k0), (AsP) + d0);         \
    load16_lds(gaA1 + (k0), (AsP) + d1);         \
    load16_lds(gbB0 + (k0), (BsP) + d0);         \
    load16_lds(gbB1 + (k0), (BsP) + d1);         \
  } while (0)

  // read position for global k-chunk l4 at row R (R = wm|wn + i*16 + ln15):
  // pos = l4 ^ s(R); s(R) = (ln15 ^ (ln15>>2)) & 3 (lane-constant).
  const int cpos = (l4 ^ ((ln15 ^ (ln15 >> 2)) & 3)) * 8;

#define FRAGS_MFMA(AsP, BsP)                                                   \
  do {                                                                         \
    short8 af[4], bf[4];                                                       \
    _Pragma("unroll") for (int i = 0; i < 4; ++i)                              \
        af[i] = *(const short8*)((AsP) + (wm + i * 16 + ln15) * 32 + cpos);    \
    _Pragma("unroll") for (int j = 0; j < 4; ++j)                              \
        bf[j] = *(const short8*)((BsP) + (wn + j * 16 + ln15) * 32 + cpos);    \
    _Pragma("unroll") for (int i = 0; i < 4; ++i)                              \
        _Pragma("unroll") for (int j = 0; j < 4; ++j)                          \
            acc[i][j] = MFMA16(bf[j], af[i], acc[i][j]); /* swapped: C^T */    \
  } while (0)

#define WAITV(n) asm volatile("s_waitcnt vmcnt(" #n ")" ::: "memory")
#define BAR() __builtin_amdgcn_s_barrier()

  STAGE(As0, Bs0, 0);
  // K/32 is even at every call site (K = 1024 or 4096): tiles pair up.
  for (int k0 = 32; k0 < K; k0 += 64) {
    // compute tile k0-32 (buf0), prefetch k0 (buf1)
    STAGE(As1, Bs1, k0);
    WAITV(4);                 // buf0's 4 loads landed; buf1's stay in flight
    BAR();
    FRAGS_MFMA(As0, Bs0);
    BAR();                    // no wave still reads buf0 -> next STAGE may hit it
    if (k0 + 32 < K) {
      // compute tile k0 (buf1), prefetch k0+32 (buf0)
      STAGE(As0, Bs0, k0 + 32);
      WAITV(4);
      BAR();
      FRAGS_MFMA(As1, Bs1);
      BAR();
    } else {
      // last tile: drain and compute
      WAITV(0);
      BAR();
      FRAGS_MFMA(As1, Bs1);
    }
  }

#undef STAGE
#undef FRAGS_MFMA
#undef WAITV
#undef BAR

  // epilogue: lane holds row = wm+i*16+ln15, cols col0..col0+3
#pragma unroll
  for (int i = 0; i < 4; ++i) {
    const int row = m0 + wm + i * 16 + ln15;
    if (GUARD && (row < rlo || row >= rhi)) continue;
    const int crow = IC ? rmap[row - m0] : row;
#pragma unroll
    for (int j = 0; j < 4; ++j) {
      const int col0 = n0 + wn + j * 16 + l4 * 4;
      float4 bv = *(const float4*)(bias + col0);
      float v0 = acc[i][j][0] + bv.x;
      float v1 = acc[i][j][1] + bv.y;
      float v2 = acc[i][j][2] + bv.z;
      float v3 = acc[i][j][3] + bv.w;
      if (EPI == 1) {
        v0 = gelu_fast(v0); v1 = gelu_fast(v1);
        v2 = gelu_fast(v2); v3 = gelu_fast(v3);
      }
      if (EPI == 2) {
        float4 o; o.x = v0; o.y = v1; o.z = v2; o.w = v3;
        *(float4*)((float*)Cp + (size_t)crow * N + col0) = o;
      } else {
        short4 s;
        s.x = f2b(v0); s.y = f2b(v1); s.z = f2b(v2); s.w = f2b(v3);
        *(short4*)((short*)Cp + (size_t)crow * N + col0) = s;
      }
    }
  }
}

// ---------------------------------------------------------------------------
// Flash attention v3: grid (S/128, NH, B), 512 thr = 8 waves x 16 q-rows.
// LDS (48KB): K tile [64 key][16 slots] (XOR-swz), V tile [128 d][8 slots]
// (XOR-swz, from pre-transposed VT), Ps per-wave P scratch. Q region (32KB)
// aliases K+V (consumed into registers before the k-loop).
// K/V staged with coalesced global_load_lds: LDS slot s of row r holds global
// chunk s^(r&7); reads use slot c^(r&7)  (involution, rule #21).
// ---------------------------------------------------------------------------
__global__ __launch_bounds__(512, 4) void flash_attn(const short* __restrict__ qkv,
                                                     const short* __restrict__ vt,
                                                     short* __restrict__ attn) {
  __shared__ alignas(16) short lds[24576];   // 48KB
  short* const Kb = lds;                     // 8192 shorts
  short* const Vb = lds + 8192;              // 8192 shorts
  short* const Ps = lds + 16384;             // 8192 shorts (8 waves x 16q x 64k)

  const int tid = threadIdx.x, lane = tid & 63, wave = tid >> 6;
  const int ln15 = lane & 15, l4 = lane >> 4, ln7 = lane & 7;
  const int q0 = blockIdx.x * 128, h = blockIdx.y, b = blockIdx.z;
  const size_t rs = H3;
  const short* qb = qkv + (size_t)b * S_ * rs + h * DH_;
  const short* kb = qb + H_;
  const short* vtb = vt + (size_t)(b * NH_ + h) * DH_ * S_;

  // ---- prologue: stage Q tile [16 chunk][128 row] into lds[0:16384) ----
#pragma unroll
  for (int it = 0; it < 4; ++it) {
    int idx = it * 512 + tid;                 // 2048 chunks of 16B
    int row = idx & 127, ch = idx >> 7;
    load16_lds(qb + (size_t)(q0 + row) * rs + ch * 8, lds + idx * 8);
  }
  __syncthreads();
  short8 qf[4];
#pragma unroll
  for (int kbi = 0; kbi < 4; ++kbi)
    qf[kbi] = *(const short8*)(lds + ((kbi * 4 + l4) * 128 + wave * 16 + ln15) * 8);
  __syncthreads();   // Q fully in regs before K/V staging overwrites it

  const f32x4 fz = {0.f, 0.f, 0.f, 0.f};
  float mr[4], lr[4];
  f32x4 o[8];
#pragma unroll
  for (int r = 0; r < 4; ++r) { mr[r] = -1e30f; lr[r] = 0.f; }
#pragma unroll
  for (int t = 0; t < 8; ++t) o[t] = fz;

  for (int kt = 0; kt < 32; ++kt) {
    const int key0 = kt * 64;
    // stage K: [64 key][16 slot16B], slot sl holds global d-chunk sl^(key&7)
#pragma unroll
    for (int it = 0; it < 2; ++it) {
      int idx = it * 512 + tid;
      int key = idx >> 4, sl = idx & 15;
      load16_lds(kb + (size_t)(key0 + key) * rs + ((sl ^ (key & 7)) * 8),
                 Kb + idx * 8);
    }
    // stage V: [128 d][8 slot16B], slot sl holds global key-chunk sl^(d&7)
#pragma unroll
    for (int it = 0; it < 2; ++it) {
      int idx = it * 512 + tid;
      int d = idx >> 3, sl = idx & 7;
      load16_lds(vtb + (size_t)d * S_ + key0 + ((sl ^ (d & 7)) * 8),
                 Vb + idx * 8);
    }
    __syncthreads();

    // QK^T: sacc[nt][r] = score[q = wave*16 + l4*4 + r][key = nt*16 + ln15]
    f32x4 sacc[4] = {fz, fz, fz, fz};
#pragma unroll
    for (int nt = 0; nt < 4; ++nt) {
      const int key = nt * 16 + ln15;
#pragma unroll
      for (int kbi = 0; kbi < 4; ++kbi) {
        short8 kf = *(const short8*)(Kb + key * 128 + (((kbi * 4 + l4) ^ ln7) * 8));
        sacc[nt] = MFMA16(qf[kbi], kf, sacc[nt]);
      }
    }
#pragma unroll
    for (int nt = 0; nt < 4; ++nt) sacc[nt] *= 0.08838834764831845f;

    // online softmax with defer-max (skip rescale while max growth <= 8)
    short* myP = Ps + wave * 1024;
#pragma unroll
    for (int r = 0; r < 4; ++r) {
      float mx = fmaxf(fmaxf(sacc[0][r], sacc[1][r]), fmaxf(sacc[2][r], sacc[3][r]));
#pragma unroll
      for (int sh = 8; sh >= 1; sh >>= 1) mx = fmaxf(mx, __shfl_xor(mx, sh, 64));
      if (!__all(mx <= mr[r] + 8.0f)) {
        float mnew = fmaxf(mr[r], mx);
        float alpha = __expf(mr[r] - mnew);
        mr[r] = mnew;
        lr[r] *= alpha;
#pragma unroll
        for (int t = 0; t < 8; ++t) o[t][r] *= alpha;
      }
      float rsum = 0.f;
#pragma unroll
      for (int nt = 0; nt < 4; ++nt) {
        float p = __expf(sacc[nt][r] - mr[r]);
        rsum += p;
        int colc = nt * 16 + ln15;
        myP[((colc >> 3) * 16 + l4 * 4 + r) * 8 + (colc & 7)] = f2b(p);
      }
#pragma unroll
      for (int sh = 8; sh >= 1; sh >>= 1) rsum += __shfl_xor(rsum, sh, 64);
      lr[r] += rsum;
    }

    // PV: o[t] += P[q][k] * V[k][d = t*16 + ln15]
#pragma unroll
    for (int kbi = 0; kbi < 2; ++kbi) {
      short8 pf = *(const short8*)(myP + ((kbi * 4 + l4) * 16 + ln15) * 8);
#pragma unroll
      for (int t = 0; t < 8; ++t) {
        short8 vf = *(const short8*)(Vb + (t * 16 + ln15) * 64 +
                                     (((kbi * 4 + l4) ^ ln7) * 8));
        o[t] = MFMA16(pf, vf, o[t]);
      }
    }
    __syncthreads();
  }

  short* ob = attn + (size_t)b * S_ * H_ + h * DH_;
#pragma unroll
  for (int r = 0; r < 4; ++r) {
    float inv = 1.0f / lr[r];
    int row = q0 + wave * 16 + l4 * 4 + r;
#pragma unroll
    for (int t = 0; t < 8; ++t)
      ob[(size_t)row * H_ + t * 16 + ln15] = f2b(o[t][r] * inv);
  }
}

// ---------------------------------------------------------------------------
__device__ __forceinline__ float block_sum(float v, float* sh, int tid) {
#pragma unroll
  for (int s = 32; s >= 1; s >>= 1) v += __shfl_xor(v, s, 64);
  if ((tid & 63) == 0) sh[tid >> 6] = v;
  __syncthreads();
  float r = sh[0] + sh[1] + sh[2] + sh[3];
  __syncthreads();
  return r;
}

template <bool ABF>
__global__ __launch_bounds__(256) void ln_res(const void* __restrict__ xa,
                                              const float* __restrict__ xb,
                                              const float* __restrict__ g,
                                              const float* __restrict__ bb,
                                              float* __restrict__ of,
                                              short* __restrict__ ob) {
  __shared__ float sh[4];
  int row = blockIdx.x, tid = threadIdx.x;
  size_t base = (size_t)row * H_ + tid * 4;
  float a0, a1, a2, a3;
  if (ABF) {
    short4 a = *(const short4*)((const short*)xa + base);
    a0 = b2f(a.x); a1 = b2f(a.y); a2 = b2f(a.z); a3 = b2f(a.w);
  } else {
    float4 a = *(const float4*)((const float*)xa + base);
    a0 = a.x; a1 = a.y; a2 = a.z; a3 = a.w;
  }
  float4 b = *(const float4*)(xb + base);
  float v0 = a0 + b.x, v1 = a1 + b.y, v2 = a2 + b.z, v3 = a3 + b.w;
  float total = block_sum(v0 + v1 + v2 + v3, sh, tid);
  float mean = total * (1.0f / H_);
  float d0 = v0 - mean, d1 = v1 - mean, d2 = v2 - mean, d3 = v3 - mean;
  float qs = block_sum(d0 * d0 + d1 * d1 + d2 * d2 + d3 * d3, sh, tid);
  float rstd = rsqrtf(qs * (1.0f / H_) + 1e-5f);
  float4 gv = *(const float4*)(g + tid * 4);
  float4 bv = *(const float4*)(bb + tid * 4);
  float r0 = d0 * rstd * gv.x + bv.x;
  float r1 = d1 * rstd * gv.y + bv.y;
  float r2 = d2 * rstd * gv.z + bv.z;
  float r3 = d3 * rstd * gv.w + bv.w;
  if (of) {
    float4 o; o.x = r0; o.y = r1; o.z = r2; o.w = r3;
    *(float4*)(of + base) = o;
  }
  if (ob) {
    short4 s;
    s.x = f2b(r0); s.y = f2b(r1); s.z = f2b(r2); s.w = f2b(r3);
    *(short4*)(ob + base) = s;
  }
}

// ---------------------------------------------------------------------------
__global__ __launch_bounds__(256) void count_experts(const int* __restrict__ mm,
                                                     int* __restrict__ meta) {
  __shared__ int c[3];
  int tid = threadIdx.x;
  if (tid < 3) c[tid] = 0;
  __syncthreads();
  int l0 = 0, l1 = 0, l2 = 0;
  for (int t = tid; t < TOK; t += 256) {
    int e = mm[t];
    l0 += (e == 0); l1 += (e == 1); l2 += (e == 2);
  }
  atomicAdd(&c[0], l0); atomicAdd(&c[1], l1); atomicAdd(&c[2], l2);
  __syncthreads();
  if (tid == 0) {
    meta[0] = c[0]; meta[1] = c[1]; meta[2] = c[2];
    meta[3] = 0;    meta[4] = c[0]; meta[5] = c[0] + c[1];
    meta[6] = 0;    meta[7] = c[0]; meta[8] = c[0] + c[1];
  }
}

__global__ __launch_bounds__(256) void assign_experts(const int* __restrict__ mm,
                                                      int* __restrict__ meta,
                                                      int* __restrict__ perm) {
  int t = blockIdx.x * 256 + threadIdx.x;
  int e = mm[t];
  int lane = threadIdx.x & 63;
  unsigned long long m0 = __ballot(e == 0);
  unsigned long long m1 = __ballot(e == 1);
  unsigned long long m2 = __ballot(e == 2);
  unsigned long long mine = (e == 0) ? m0 : ((e == 1) ? m1 : m2);
  int rank = __popcll(mine & ((1ULL << lane) - 1ULL));
  int leader = __ffsll((unsigned long long)mine) - 1;
  int wb = 0;
  if (lane == leader) wb = atomicAdd(meta + 6 + e, __popcll(mine));
  wb = __shfl(wb, leader, 64);
  perm[wb + rank] = t;
}

// ---------------------------------------------------------------------------
extern "C" void kernel_launch(void* const* d_in, const int* in_sizes, int n_in,
                              void* d_out, int out_size, void* d_ws, size_t ws_size,
                              hipStream_t stream) {
  const float* x    = (const float*)d_in[0];
  const int*   mm   = (const int*)d_in[1];
  const float* Wqkv = (const float*)d_in[3];
  const float* bqkv = (const float*)d_in[4];
  const float* Wout = (const float*)d_in[5];
  const float* bout = (const float*)d_in[6];
  const float* ln1g = (const float*)d_in[7];
  const float* ln1b = (const float*)d_in[8];
  const float* W1[3] = {(const float*)d_in[9],  (const float*)d_in[13], (const float*)d_in[17]};
  const float* b1[3] = {(const float*)d_in[10], (const float*)d_in[14], (const float*)d_in[18]};
  const float* W2[3] = {(const float*)d_in[11], (const float*)d_in[15], (const float*)d_in[19]};
  const float* b2[3] = {(const float*)d_in[12], (const float*)d_in[16], (const float*)d_in[20]};
  const float* ln2g = (const float*)d_in[21];
  const float* ln2b = (const float*)d_in[22];

  char* Wp = (char*)d_ws;
  size_t off = 0;
  auto take = [&](size_t bytes) {
    char* p = Wp + off;
    off += (bytes + 255) & ~(size_t)255;
    return p;
  };
  short* WT = (short*)take((size_t)3 * FF_ * H_ * 2);          // 24 MB
  char* R_A = take((size_t)TOK * H_ * 2);                      // 32 MB
  char* R_Q = take((size_t)TOK * FF_ * 2);                     // 128 MB
  char* R_P = take((size_t)TOK * H_ * 4);                      // 64 MB
  int* PERM = (int*)take((size_t)TOK * 4);
  int* META = (int*)take(256);

  short* XB   = (short*)R_A;
  short* ATTN = (short*)R_A;
  short* X1B  = (short*)R_A;
  short* QKV  = (short*)R_Q;
  short* HBUF = (short*)R_Q;
  float* PROJ = (float*)R_P;
  float* EOUT = (float*)R_P;
  short* VT   = (short*)R_P;   // 32 MB, consumed by flash_attn before PROJ

  dim3 tb(32, 8);

  cvt_bf16<<<(TOK * H_ / 4 + 255) / 256, 256, 0, stream>>>(x, XB, TOK * H_ / 4);

  transpose_cvt<<<dim3(H3 / 32, H_ / 32), tb, 0, stream>>>(Wqkv, WT, H_, H3);

  gemm_bt<0, false, false, false><<<dim3(TOK / 128, H3 / 128, 1), 256, 0, stream>>>(
      XB, WT, QKV, Ptr3{{bqkv, bqkv, bqkv}}, H3, H_, nullptr, nullptr);

  transpose_v<<<dim3(S_ / 32, DH_ / 32, B_ * NH_), tb, 0, stream>>>(QKV, VT);

  flash_attn<<<dim3(S_ / 128, NH_, B_), 512, 0, stream>>>(QKV, VT, ATTN);

  transpose_cvt<<<dim3(H_ / 32, H_ / 32), tb, 0, stream>>>(Wout, WT, H_, H_);

  gemm_bt<2, false, false, false><<<dim3(TOK / 128, H_ / 128, 1), 256, 0, stream>>>(
      ATTN, WT, PROJ, Ptr3{{bout, bout, bout}}, H_, H_, nullptr, nullptr);

  ln_res<false><<<TOK, 256, 0, stream>>>(x, PROJ, ln1g, ln1b, nullptr, X1B);

  count_experts<<<1, 256, 0, stream>>>(mm, META);
  assign_experts<<<TOK / 256, 256, 0, stream>>>(mm, META, PERM);

  for (int e = 0; e < 3; ++e)
    transpose_cvt<<<dim3(FF_ / 32, H_ / 32), tb, 0, stream>>>(
        W1[e], WT + (size_t)e * FF_ * H_, H_, FF_);

  gemm_bt<1, true, false, true><<<dim3(TOK / 128, FF_ / 128, 3), 256, 0, stream>>>(
      X1B, WT, HBUF, Ptr3{{b1[0], b1[1], b1[2]}}, FF_, H_, PERM, META);

  for (int e = 0; e < 3; ++e)
    transpose_cvt<<<dim3(H_ / 32, FF_ / 32), tb, 0, stream>>>(
        W2[e], WT + (size_t)e * H_ * FF_, FF_, H_);

  gemm_bt<2, false, true, true><<<dim3(TOK / 128, H_ / 128, 3), 256, 0, stream>>>(
      HBUF, WT, EOUT, Ptr3{{b2[0], b2[1], b2[2]}}, H_, FF_, PERM, META);

  ln_res<true><<<TOK, 256, 0, stream>>>(X1B, EOUT, ln2g, ln2b, (float*)d_out, nullptr);
}

// Round 8
// 1323.345 us; speedup vs baseline: 1.0057x; 1.0057x over previous
//
#include <hip/hip_runtime.h>

// ---------------------------------------------------------------------------
// ImprovedVietnameseVQAModel: MHA + LN + modality-routed expert FFN + LN
// B=8 S=2048 H=1024 NH=8 DH=128 FF=4096, fp32 in/out, bf16 MFMA compute.
// R10: 256x256 tile with BK=32 and 64KB total LDS (de-risked from R8/R9's
//      128KB, which failed twice with no verdict -- every kernel that has
//      run here used <=62KB). Keeps the intensity thesis: 8 waves x 32 MFMA
//      per 32KB staged = 8 MFMA/KB (2x R6). Same R6 sync structure (2-phase
//      static double buffer, one __syncthreads per step) and same R6 chunk
//      swizzle s(row)=(row^(row>>2))&3 (measured-correct, known bank cost).
// ---------------------------------------------------------------------------

#define B_ 8
#define S_ 2048
#define H_ 1024
#define NH_ 8
#define DH_ 128
#define FF_ 4096
#define TOK (B_ * S_)         // 16384
#define H3 (3 * H_)           // 3072

using short8 = __attribute__((ext_vector_type(8))) short;
using f32x4  = __attribute__((ext_vector_type(4))) float;

__device__ __forceinline__ short f2b(float f) {
  union { float f; unsigned u; } x; x.f = f;
  unsigned r = x.u + 0x7fffu + ((x.u >> 16) & 1u);
  return (short)(r >> 16);
}

__device__ __forceinline__ float b2f(short s) {
  union { unsigned u; float f; } x;
  x.u = ((unsigned)(unsigned short)s) << 16;
  return x.f;
}

// gelu(v) = v * sigmoid(1.5957691216*(v + 0.044715 v^3)); |err| ~1e-3 << bf16
__device__ __forceinline__ float gelu_fast(float v) {
  float u = 1.5957691216057308f * (v + 0.044715f * v * v * v);
  return v * __builtin_amdgcn_rcpf(1.0f + __expf(-u));
}

__device__ __forceinline__ void load16_lds(const void* g, void* l) {
  __builtin_amdgcn_global_load_lds(
      (__attribute__((address_space(1))) void*)(g),
      (__attribute__((address_space(3))) void*)(l), 16, 0, 0);
}

#define MFMA16(a, b, c) __builtin_amdgcn_mfma_f32_16x16x32_bf16((a), (b), (c), 0, 0, 0)

struct Ptr3 { const float* p[3]; };

// ---------------------------------------------------------------------------
__global__ __launch_bounds__(256) void cvt_bf16(const float* __restrict__ in,
                                                short* __restrict__ out, int n4) {
  int i = blockIdx.x * 256 + threadIdx.x;
  if (i >= n4) return;
  float4 v = *(const float4*)(in + (size_t)i * 4);
  short4 s;
  s.x = f2b(v.x); s.y = f2b(v.y); s.z = f2b(v.z); s.w = f2b(v.w);
  *(short4*)(out + (size_t)i * 4) = s;
}

// ---------------------------------------------------------------------------
__global__ __launch_bounds__(256) void transpose_cvt(const float* __restrict__ in,
                                                     short* __restrict__ out,
                                                     int R, int C) {
  __shared__ float t[32][33];
  int c0 = blockIdx.x * 32, r0 = blockIdx.y * 32;
  int tx = threadIdx.x, ty = threadIdx.y;
#pragma unroll
  for (int i = 0; i < 4; ++i)
    t[ty + i * 8][tx] = in[(size_t)(r0 + ty + i * 8) * C + c0 + tx];
  __syncthreads();
#pragma unroll
  for (int i = 0; i < 4; ++i)
    out[(size_t)(c0 + ty + i * 8) * R + r0 + tx] = f2b(t[tx][ty + i * 8]);
}

// ---------------------------------------------------------------------------
// V pre-transpose: QKV[b,key, 2H + h*128 + d] -> VT[(b*NH+h)*128 + d][key]
// so flash_attn can stage V tiles with coalesced global_load_lds.
// ---------------------------------------------------------------------------
__global__ __launch_bounds__(256) void transpose_v(const short* __restrict__ qkv,
                                                   short* __restrict__ vt) {
  __shared__ short t[32][33];
  int key0 = blockIdx.x * 32, d0 = blockIdx.y * 32, bh = blockIdx.z;
  int b = bh >> 3, h = bh & 7;
  int tx = threadIdx.x, ty = threadIdx.y;
  const short* src = qkv + (size_t)(b * S_ + key0) * H3 + 2 * H_ + h * DH_ + d0;
#pragma unroll
  for (int i = 0; i < 4; ++i)
    t[ty + i * 8][tx] = src[(size_t)(ty + i * 8) * H3 + tx];   // t[key][d]
  __syncthreads();
  short* dst = vt + ((size_t)bh * DH_ + d0) * S_ + key0;
#pragma unroll
  for (int i = 0; i < 4; ++i)
    dst[(size_t)(ty + i * 8) * S_ + tx] = t[tx][ty + i * 8];   // VT[d][key]
}

// ---------------------------------------------------------------------------
// Generic bf16 GEMM:  C[M,N] = A[M,K] @ Bt[N,K]^T (+bias, epilogue)
// 256x256 tile, BK=32, 512 thr = 8 waves (2M x 4N), per-wave 128x64 output
// (8x4 frags of 16x16x32, 32 MFMA per K-step per wave).
// Staging: sr = tid>>2 (row 0..127), sl = tid&3; thread loads rows sr and
// 128+sr (64B-contiguous per row, 4 lanes/row). LDS [256 row][4 chunk16B],
// tid-linear dest; slot sl holds global chunk sl^s(row), s=(row^(row>>2))&3
// (same measured-correct swizzle as the 1318us R6 kernel). Reads use
// pos = l4 ^ s(row), lane-constant. 2-phase static double buffers, one
// __syncthreads per K-step. LDS total 64KB.
// MFMA operands swapped: acc[i][j] reg r holds m = wm+i*16+(lane&15),
// n = wn+j*16+(lane>>4)*4+r  -> 4 consecutive cols per lane -> vector stores.
// EPI: 0 = bf16 C (+bias), 1 = bf16 C (+bias, fast GELU), 2 = fp32 C (+bias)
// ---------------------------------------------------------------------------
template <int EPI, bool IA, bool IC, bool GUARD>
__global__ __launch_bounds__(512, 2) void gemm_bt(const short* __restrict__ A,
                                                  const short* __restrict__ Bt,
                                                  void* __restrict__ Cp, Ptr3 bias3,
                                                  int N, int K,
                                                  const int* __restrict__ perm,
                                                  const int* __restrict__ meta) {
  const int m0 = blockIdx.x * 256, n0 = blockIdx.y * 256, e = blockIdx.z;
  int rlo = 0, rhi = 0x7fffffff;
  if (GUARD) {
    rlo = meta[3 + e];
    rhi = rlo + meta[e];
    if (m0 >= rhi || m0 + 256 <= rlo) return;
  }
  const short* Bte = Bt + (size_t)e * N * K;
  const float* bias = bias3.p[e];

  __shared__ alignas(16) short As0[8192];    // 16KB each, 64KB total
  __shared__ alignas(16) short As1[8192];
  __shared__ alignas(16) short Bs0[8192];
  __shared__ alignas(16) short Bs1[8192];

  const int tid = threadIdx.x;
  const int lane = tid & 63, wave = tid >> 6;
  const int ln15 = lane & 15, l4 = lane >> 4;
  const int wm = (wave & 1) * 128, wn = (wave >> 1) * 64;
  const int swz = (ln15 ^ (ln15 >> 2)) & 3;  // = s(row) for row = ...+ln15

  // staging geometry: sr = tid>>2 (row 0..127), sl = tid&3 (16B slot);
  // this thread covers rows sr and 128+sr (same swizzle key s0 for both).
  const int sr = tid >> 2, sl = tid & 3;
  const int s0 = (sr ^ (sr >> 2)) & 3;
  const int gch = (sl ^ s0) * 8;             // global chunk this slot holds
  int mr0 = m0 + sr, mr1 = m0 + 128 + sr;
  if (IA) { mr0 = perm[mr0]; mr1 = perm[mr1]; }
  const short* gA0 = A + (size_t)mr0 * K + gch;
  const short* gA1 = A + (size_t)mr1 * K + gch;
  const short* gB0 = Bte + (size_t)(n0 + sr) * K + gch;
  const short* gB1 = Bte + (size_t)(n0 + 128 + sr) * K + gch;
  const int d0 = tid * 8;                    // LDS dst (shorts), rows 0..127
  const int d1 = 4096 + tid * 8;             // rows 128..255

  const f32x4 fz = {0.f, 0.f, 0.f, 0.f};
  f32x4 acc[8][4];
#pragma unroll
  for (int i = 0; i < 8; ++i)
#pragma unroll
    for (int j = 0; j < 4; ++j) acc[i][j] = fz;

#define STAGE(AsP, BsP, k0)                  \
  do {                                       \
    load16_lds(gA0 + (k0), (AsP) + d0);      \
    load16_lds(gA1 + (k0), (AsP) + d1);      \
    load16_lds(gB0 + (k0), (BsP) + d0);      \
    load16_lds(gB1 + (k0), (BsP) + d1);      \
  } while (0)

#define FRAGS_MFMA(AsP, BsP)                                                    \
  do {                                                                          \
    const int pos = (l4 ^ swz) * 8;                                             \
    short8 af[8], bf[4];                                                        \
    _Pragma("unroll") for (int i = 0; i < 8; ++i)                               \
        af[i] = *(const short8*)((AsP) + (wm + i * 16 + ln15) * 32 + pos);      \
    _Pragma("unroll") for (int j = 0; j < 4; ++j)                               \
        bf[j] = *(const short8*)((BsP) + (wn + j * 16 + ln15) * 32 + pos);      \
    _Pragma("unroll") for (int i = 0; i < 8; ++i)                               \
        _Pragma("unroll") for (int j = 0; j < 4; ++j)                           \
            acc[i][j] = MFMA16(bf[j], af[i], acc[i][j]); /* swapped: C^T */     \
  } while (0)

  STAGE(As0, Bs0, 0);
  __syncthreads();                  // drains prologue loads
  int k0 = 32;
  for (; k0 < K - 32; k0 += 64) {
    STAGE(As1, Bs1, k0);            // prefetch odd tile (in flight over MFMA)
    FRAGS_MFMA(As0, Bs0);
    __syncthreads();
    STAGE(As0, Bs0, k0 + 32);       // prefetch even tile
    FRAGS_MFMA(As1, Bs1);
    __syncthreads();
  }
  STAGE(As1, Bs1, k0);              // last tile (k0 == K-32 since K/32 even)
  FRAGS_MFMA(As0, Bs0);
  __syncthreads();
  FRAGS_MFMA(As1, Bs1);

#undef STAGE
#undef FRAGS_MFMA

  // epilogue: lane holds row = wm+i*16+ln15, cols col0..col0+3
#pragma unroll
  for (int i = 0; i < 8; ++i) {
    const int row = m0 + wm + i * 16 + ln15;
    if (GUARD && (row < rlo || row >= rhi)) continue;
    const int crow = IC ? perm[row] : row;
#pragma unroll
    for (int j = 0; j < 4; ++j) {
      const int col0 = n0 + wn + j * 16 + l4 * 4;
      float4 bv = *(const float4*)(bias + col0);
      float v0 = acc[i][j][0] + bv.x;
      float v1 = acc[i][j][1] + bv.y;
      float v2 = acc[i][j][2] + bv.z;
      float v3 = acc[i][j][3] + bv.w;
      if (EPI == 1) {
        v0 = gelu_fast(v0); v1 = gelu_fast(v1);
        v2 = gelu_fast(v2); v3 = gelu_fast(v3);
      }
      if (EPI == 2) {
        float4 o; o.x = v0; o.y = v1; o.z = v2; o.w = v3;
        *(float4*)((float*)Cp + (size_t)crow * N + col0) = o;
      } else {
        short4 s;
        s.x = f2b(v0); s.y = f2b(v1); s.z = f2b(v2); s.w = f2b(v3);
        *(short4*)((short*)Cp + (size_t)crow * N + col0) = s;
      }
    }
  }
}

// ---------------------------------------------------------------------------
// Flash attention v3: grid (S/128, NH, B), 512 thr = 8 waves x 16 q-rows.
// LDS (48KB): K tile [64 key][16 slots] (XOR-swz), V tile [128 d][8 slots]
// (XOR-swz, from pre-transposed VT), Ps per-wave P scratch. Q region (32KB)
// aliases K+V (consumed into registers before the k-loop).
// K/V staged with coalesced global_load_lds: LDS slot s of row r holds global
// chunk s^(r&7); reads use slot c^(r&7)  (involution, rule #21).
// ---------------------------------------------------------------------------
__global__ __launch_bounds__(512, 4) void flash_attn(const short* __restrict__ qkv,
                                                     const short* __restrict__ vt,
                                                     short* __restrict__ attn) {
  __shared__ alignas(16) short lds[24576];   // 48KB
  short* const Kb = lds;                     // 8192 shorts
  short* const Vb = lds + 8192;              // 8192 shorts
  short* const Ps = lds + 16384;             // 8192 shorts (8 waves x 16q x 64k)

  const int tid = threadIdx.x, lane = tid & 63, wave = tid >> 6;
  const int ln15 = lane & 15, l4 = lane >> 4, ln7 = lane & 7;
  const int q0 = blockIdx.x * 128, h = blockIdx.y, b = blockIdx.z;
  const size_t rs = H3;
  const short* qb = qkv + (size_t)b * S_ * rs + h * DH_;
  const short* kb = qb + H_;
  const short* vtb = vt + (size_t)(b * NH_ + h) * DH_ * S_;

  // ---- prologue: stage Q tile [16 chunk][128 row] into lds[0:16384) ----
#pragma unroll
  for (int it = 0; it < 4; ++it) {
    int idx = it * 512 + tid;                 // 2048 chunks of 16B
    int row = idx & 127, ch = idx >> 7;
    load16_lds(qb + (size_t)(q0 + row) * rs + ch * 8, lds + idx * 8);
  }
  __syncthreads();
  short8 qf[4];
#pragma unroll
  for (int kbi = 0; kbi < 4; ++kbi)
    qf[kbi] = *(const short8*)(lds + ((kbi * 4 + l4) * 128 + wave * 16 + ln15) * 8);
  __syncthreads();   // Q fully in regs before K/V staging overwrites it

  const f32x4 fz = {0.f, 0.f, 0.f, 0.f};
  float mr[4], lr[4];
  f32x4 o[8];
#pragma unroll
  for (int r = 0; r < 4; ++r) { mr[r] = -1e30f; lr[r] = 0.f; }
#pragma unroll
  for (int t = 0; t < 8; ++t) o[t] = fz;

  for (int kt = 0; kt < 32; ++kt) {
    const int key0 = kt * 64;
    // stage K: [64 key][16 slot16B], slot sl holds global d-chunk sl^(key&7)
#pragma unroll
    for (int it = 0; it < 2; ++it) {
      int idx = it * 512 + tid;
      int key = idx >> 4, sl = idx & 15;
      load16_lds(kb + (size_t)(key0 + key) * rs + ((sl ^ (key & 7)) * 8),
                 Kb + idx * 8);
    }
    // stage V: [128 d][8 slot16B], slot sl holds global key-chunk sl^(d&7)
#pragma unroll
    for (int it = 0; it < 2; ++it) {
      int idx = it * 512 + tid;
      int d = idx >> 3, sl = idx & 7;
      load16_lds(vtb + (size_t)d * S_ + key0 + ((sl ^ (d & 7)) * 8),
                 Vb + idx * 8);
    }
    __syncthreads();

    // QK^T: sacc[nt][r] = score[q = wave*16 + l4*4 + r][key = nt*16 + ln15]
    f32x4 sacc[4] = {fz, fz, fz, fz};
#pragma unroll
    for (int nt = 0; nt < 4; ++nt) {
      const int key = nt * 16 + ln15;
#pragma unroll
      for (int kbi = 0; kbi < 4; ++kbi) {
        short8 kf = *(const short8*)(Kb + key * 128 + (((kbi * 4 + l4) ^ ln7) * 8));
        sacc[nt] = MFMA16(qf[kbi], kf, sacc[nt]);
      }
    }
#pragma unroll
    for (int nt = 0; nt < 4; ++nt) sacc[nt] *= 0.08838834764831845f;

    // online softmax with defer-max (skip rescale while max growth <= 8)
    short* myP = Ps + wave * 1024;
#pragma unroll
    for (int r = 0; r < 4; ++r) {
      float mx = fmaxf(fmaxf(sacc[0][r], sacc[1][r]), fmaxf(sacc[2][r], sacc[3][r]));
#pragma unroll
      for (int sh = 8; sh >= 1; sh >>= 1) mx = fmaxf(mx, __shfl_xor(mx, sh, 64));
      if (!__all(mx <= mr[r] + 8.0f)) {
        float mnew = fmaxf(mr[r], mx);
        float alpha = __expf(mr[r] - mnew);
        mr[r] = mnew;
        lr[r] *= alpha;
#pragma unroll
        for (int t = 0; t < 8; ++t) o[t][r] *= alpha;
      }
      float rsum = 0.f;
#pragma unroll
      for (int nt = 0; nt < 4; ++nt) {
        float p = __expf(sacc[nt][r] - mr[r]);
        rsum += p;
        int colc = nt * 16 + ln15;
        myP[((colc >> 3) * 16 + l4 * 4 + r) * 8 + (colc & 7)] = f2b(p);
      }
#pragma unroll
      for (int sh = 8; sh >= 1; sh >>= 1) rsum += __shfl_xor(rsum, sh, 64);
      lr[r] += rsum;
    }

    // PV: o[t] += P[q][k] * V[k][d = t*16 + ln15]
#pragma unroll
    for (int kbi = 0; kbi < 2; ++kbi) {
      short8 pf = *(const short8*)(myP + ((kbi * 4 + l4) * 16 + ln15) * 8);
#pragma unroll
      for (int t = 0; t < 8; ++t) {
        short8 vf = *(const short8*)(Vb + (t * 16 + ln15) * 64 +
                                     (((kbi * 4 + l4) ^ ln7) * 8));
        o[t] = MFMA16(pf, vf, o[t]);
      }
    }
    __syncthreads();
  }

  short* ob = attn + (size_t)b * S_ * H_ + h * DH_;
#pragma unroll
  for (int r = 0; r < 4; ++r) {
    float inv = 1.0f / lr[r];
    int row = q0 + wave * 16 + l4 * 4 + r;
#pragma unroll
    for (int t = 0; t < 8; ++t)
      ob[(size_t)row * H_ + t * 16 + ln15] = f2b(o[t][r] * inv);
  }
}

// ---------------------------------------------------------------------------
__device__ __forceinline__ float block_sum(float v, float* sh, int tid) {
#pragma unroll
  for (int s = 32; s >= 1; s >>= 1) v += __shfl_xor(v, s, 64);
  if ((tid & 63) == 0) sh[tid >> 6] = v;
  __syncthreads();
  float r = sh[0] + sh[1] + sh[2] + sh[3];
  __syncthreads();
  return r;
}

template <bool ABF>
__global__ __launch_bounds__(256) void ln_res(const void* __restrict__ xa,
                                              const float* __restrict__ xb,
                                              const float* __restrict__ g,
                                              const float* __restrict__ bb,
                                              float* __restrict__ of,
                                              short* __restrict__ ob) {
  __shared__ float sh[4];
  int row = blockIdx.x, tid = threadIdx.x;
  size_t base = (size_t)row * H_ + tid * 4;
  float a0, a1, a2, a3;
  if (ABF) {
    short4 a = *(const short4*)((const short*)xa + base);
    a0 = b2f(a.x); a1 = b2f(a.y); a2 = b2f(a.z); a3 = b2f(a.w);
  } else {
    float4 a = *(const float4*)((const float*)xa + base);
    a0 = a.x; a1 = a.y; a2 = a.z; a3 = a.w;
  }
  float4 b = *(const float4*)(xb + base);
  float v0 = a0 + b.x, v1 = a1 + b.y, v2 = a2 + b.z, v3 = a3 + b.w;
  float total = block_sum(v0 + v1 + v2 + v3, sh, tid);
  float mean = total * (1.0f / H_);
  float d0 = v0 - mean, d1 = v1 - mean, d2 = v2 - mean, d3 = v3 - mean;
  float qs = block_sum(d0 * d0 + d1 * d1 + d2 * d2 + d3 * d3, sh, tid);
  float rstd = rsqrtf(qs * (1.0f / H_) + 1e-5f);
  float4 gv = *(const float4*)(g + tid * 4);
  float4 bv = *(const float4*)(bb + tid * 4);
  float r0 = d0 * rstd * gv.x + bv.x;
  float r1 = d1 * rstd * gv.y + bv.y;
  float r2 = d2 * rstd * gv.z + bv.z;
  float r3 = d3 * rstd * gv.w + bv.w;
  if (of) {
    float4 o; o.x = r0; o.y = r1; o.z = r2; o.w = r3;
    *(float4*)(of + base) = o;
  }
  if (ob) {
    short4 s;
    s.x = f2b(r0); s.y = f2b(r1); s.z = f2b(r2); s.w = f2b(r3);
    *(short4*)(ob + base) = s;
  }
}

// ---------------------------------------------------------------------------
__global__ __launch_bounds__(256) void count_experts(const int* __restrict__ mm,
                                                     int* __restrict__ meta) {
  __shared__ int c[3];
  int tid = threadIdx.x;
  if (tid < 3) c[tid] = 0;
  __syncthreads();
  int l0 = 0, l1 = 0, l2 = 0;
  for (int t = tid; t < TOK; t += 256) {
    int e = mm[t];
    l0 += (e == 0); l1 += (e == 1); l2 += (e == 2);
  }
  atomicAdd(&c[0], l0); atomicAdd(&c[1], l1); atomicAdd(&c[2], l2);
  __syncthreads();
  if (tid == 0) {
    meta[0] = c[0]; meta[1] = c[1]; meta[2] = c[2];
    meta[3] = 0;    meta[4] = c[0]; meta[5] = c[0] + c[1];
    meta[6] = 0;    meta[7] = c[0]; meta[8] = c[0] + c[1];
  }
}

__global__ __launch_bounds__(256) void assign_experts(const int* __restrict__ mm,
                                                      int* __restrict__ meta,
                                                      int* __restrict__ perm) {
  int t = blockIdx.x * 256 + threadIdx.x;
  int e = mm[t];
  int lane = threadIdx.x & 63;
  unsigned long long m0 = __ballot(e == 0);
  unsigned long long m1 = __ballot(e == 1);
  unsigned long long m2 = __ballot(e == 2);
  unsigned long long mine = (e == 0) ? m0 : ((e == 1) ? m1 : m2);
  int rank = __popcll(mine & ((1ULL << lane) - 1ULL));
  int leader = __ffsll((unsigned long long)mine) - 1;
  int wb = 0;
  if (lane == leader) wb = atomicAdd(meta + 6 + e, __popcll(mine));
  wb = __shfl(wb, leader, 64);
  perm[wb + rank] = t;
}

// ---------------------------------------------------------------------------
extern "C" void kernel_launch(void* const* d_in, const int* in_sizes, int n_in,
                              void* d_out, int out_size, void* d_ws, size_t ws_size,
                              hipStream_t stream) {
  const float* x    = (const float*)d_in[0];
  const int*   mm   = (const int*)d_in[1];
  const float* Wqkv = (const float*)d_in[3];
  const float* bqkv = (const float*)d_in[4];
  const float* Wout = (const float*)d_in[5];
  const float* bout = (const float*)d_in[6];
  const float* ln1g = (const float*)d_in[7];
  const float* ln1b = (const float*)d_in[8];
  const float* W1[3] = {(const float*)d_in[9],  (const float*)d_in[13], (const float*)d_in[17]};
  const float* b1[3] = {(const float*)d_in[10], (const float*)d_in[14], (const float*)d_in[18]};
  const float* W2[3] = {(const float*)d_in[11], (const float*)d_in[15], (const float*)d_in[19]};
  const float* b2[3] = {(const float*)d_in[12], (const float*)d_in[16], (const float*)d_in[20]};
  const float* ln2g = (const float*)d_in[21];
  const float* ln2b = (const float*)d_in[22];

  char* Wp = (char*)d_ws;
  size_t off = 0;
  auto take = [&](size_t bytes) {
    char* p = Wp + off;
    off += (bytes + 255) & ~(size_t)255;
    return p;
  };
  short* WT = (short*)take((size_t)3 * FF_ * H_ * 2);          // 24 MB
  char* R_A = take((size_t)TOK * H_ * 2);                      // 32 MB
  char* R_Q = take((size_t)TOK * FF_ * 2);                     // 128 MB
  char* R_P = take((size_t)TOK * H_ * 4);                      // 64 MB
  int* PERM = (int*)take((size_t)TOK * 4);
  int* META = (int*)take(256);

  short* XB   = (short*)R_A;
  short* ATTN = (short*)R_A;
  short* X1B  = (short*)R_A;
  short* QKV  = (short*)R_Q;
  short* HBUF = (short*)R_Q;
  float* PROJ = (float*)R_P;
  float* EOUT = (float*)R_P;
  short* VT   = (short*)R_P;   // 32 MB, consumed by flash_attn before PROJ

  dim3 tb(32, 8);

  cvt_bf16<<<(TOK * H_ / 4 + 255) / 256, 256, 0, stream>>>(x, XB, TOK * H_ / 4);

  transpose_cvt<<<dim3(H3 / 32, H_ / 32), tb, 0, stream>>>(Wqkv, WT, H_, H3);

  gemm_bt<0, false, false, false><<<dim3(TOK / 256, H3 / 256, 1), 512, 0, stream>>>(
      XB, WT, QKV, Ptr3{{bqkv, bqkv, bqkv}}, H3, H_, nullptr, nullptr);

  transpose_v<<<dim3(S_ / 32, DH_ / 32, B_ * NH_), tb, 0, stream>>>(QKV, VT);

  flash_attn<<<dim3(S_ / 128, NH_, B_), 512, 0, stream>>>(QKV, VT, ATTN);

  transpose_cvt<<<dim3(H_ / 32, H_ / 32), tb, 0, stream>>>(Wout, WT, H_, H_);

  gemm_bt<2, false, false, false><<<dim3(TOK / 256, H_ / 256, 1), 512, 0, stream>>>(
      ATTN, WT, PROJ, Ptr3{{bout, bout, bout}}, H_, H_, nullptr, nullptr);

  ln_res<false><<<TOK, 256, 0, stream>>>(x, PROJ, ln1g, ln1b, nullptr, X1B);

  count_experts<<<1, 256, 0, stream>>>(mm, META);
  assign_experts<<<TOK / 256, 256, 0, stream>>>(mm, META, PERM);

  for (int e = 0; e < 3; ++e)
    transpose_cvt<<<dim3(FF_ / 32, H_ / 32), tb, 0, stream>>>(
        W1[e], WT + (size_t)e * FF_ * H_, H_, FF_);

  gemm_bt<1, true, false, true><<<dim3(TOK / 256, FF_ / 256, 3), 512, 0, stream>>>(
      X1B, WT, HBUF, Ptr3{{b1[0], b1[1], b1[2]}}, FF_, H_, PERM, META);

  for (int e = 0; e < 3; ++e)
    transpose_cvt<<<dim3(H_ / 32, FF_ / 32), tb, 0, stream>>>(
        W2[e], WT + (size_t)e * H_ * FF_, FF_, H_);

  gemm_bt<2, false, true, true><<<dim3(TOK / 256, H_ / 256, 3), 512, 0, stream>>>(
      HBUF, WT, EOUT, Ptr3{{b2[0], b2[1], b2[2]}}, H_, FF_, PERM, META);

  ln_res<true><<<TOK, 256, 0, stream>>>(X1B, EOUT, ln2g, ln2b, (float*)d_out, nullptr);
}

// Round 9
// 1264.259 us; speedup vs baseline: 1.0527x; 1.0467x over previous
//
#include <hip/hip_runtime.h>

// ---------------------------------------------------------------------------
// ImprovedVietnameseVQAModel: MHA + LN + modality-routed expert FFN + LN
// B=8 S=2048 H=1024 NH=8 DH=128 FF=4096, fp32 in/out, bf16 MFMA compute.
// R11 = R10 (256x256, BK=32, 64KB LDS, 2-phase static dbuf) + T4 counted
//       vmcnt + T5 setprio. R10's __syncthreads was drain-0: each step paid
//       its own prefetch's full latency (VALUBusy 6.7%, MfmaUtil 18% = pure
//       wait). Now: STAGE(next) -> vmcnt(4) [prev tile only] -> s_barrier ->
//       setprio(1)+MFMA+setprio(0) -> s_barrier. Sync structure correctness
//       pre-screened by R7 (identical pattern, absmax unchanged).
// ---------------------------------------------------------------------------

#define B_ 8
#define S_ 2048
#define H_ 1024
#define NH_ 8
#define DH_ 128
#define FF_ 4096
#define TOK (B_ * S_)         // 16384
#define H3 (3 * H_)           // 3072

using short8 = __attribute__((ext_vector_type(8))) short;
using f32x4  = __attribute__((ext_vector_type(4))) float;

__device__ __forceinline__ short f2b(float f) {
  union { float f; unsigned u; } x; x.f = f;
  unsigned r = x.u + 0x7fffu + ((x.u >> 16) & 1u);
  return (short)(r >> 16);
}

__device__ __forceinline__ float b2f(short s) {
  union { unsigned u; float f; } x;
  x.u = ((unsigned)(unsigned short)s) << 16;
  return x.f;
}

// gelu(v) = v * sigmoid(1.5957691216*(v + 0.044715 v^3)); |err| ~1e-3 << bf16
__device__ __forceinline__ float gelu_fast(float v) {
  float u = 1.5957691216057308f * (v + 0.044715f * v * v * v);
  return v * __builtin_amdgcn_rcpf(1.0f + __expf(-u));
}

__device__ __forceinline__ void load16_lds(const void* g, void* l) {
  __builtin_amdgcn_global_load_lds(
      (__attribute__((address_space(1))) void*)(g),
      (__attribute__((address_space(3))) void*)(l), 16, 0, 0);
}

#define MFMA16(a, b, c) __builtin_amdgcn_mfma_f32_16x16x32_bf16((a), (b), (c), 0, 0, 0)

struct Ptr3 { const float* p[3]; };

// ---------------------------------------------------------------------------
__global__ __launch_bounds__(256) void cvt_bf16(const float* __restrict__ in,
                                                short* __restrict__ out, int n4) {
  int i = blockIdx.x * 256 + threadIdx.x;
  if (i >= n4) return;
  float4 v = *(const float4*)(in + (size_t)i * 4);
  short4 s;
  s.x = f2b(v.x); s.y = f2b(v.y); s.z = f2b(v.z); s.w = f2b(v.w);
  *(short4*)(out + (size_t)i * 4) = s;
}

// ---------------------------------------------------------------------------
__global__ __launch_bounds__(256) void transpose_cvt(const float* __restrict__ in,
                                                     short* __restrict__ out,
                                                     int R, int C) {
  __shared__ float t[32][33];
  int c0 = blockIdx.x * 32, r0 = blockIdx.y * 32;
  int tx = threadIdx.x, ty = threadIdx.y;
#pragma unroll
  for (int i = 0; i < 4; ++i)
    t[ty + i * 8][tx] = in[(size_t)(r0 + ty + i * 8) * C + c0 + tx];
  __syncthreads();
#pragma unroll
  for (int i = 0; i < 4; ++i)
    out[(size_t)(c0 + ty + i * 8) * R + r0 + tx] = f2b(t[tx][ty + i * 8]);
}

// ---------------------------------------------------------------------------
// V pre-transpose: QKV[b,key, 2H + h*128 + d] -> VT[(b*NH+h)*128 + d][key]
// so flash_attn can stage V tiles with coalesced global_load_lds.
// ---------------------------------------------------------------------------
__global__ __launch_bounds__(256) void transpose_v(const short* __restrict__ qkv,
                                                   short* __restrict__ vt) {
  __shared__ short t[32][33];
  int key0 = blockIdx.x * 32, d0 = blockIdx.y * 32, bh = blockIdx.z;
  int b = bh >> 3, h = bh & 7;
  int tx = threadIdx.x, ty = threadIdx.y;
  const short* src = qkv + (size_t)(b * S_ + key0) * H3 + 2 * H_ + h * DH_ + d0;
#pragma unroll
  for (int i = 0; i < 4; ++i)
    t[ty + i * 8][tx] = src[(size_t)(ty + i * 8) * H3 + tx];   // t[key][d]
  __syncthreads();
  short* dst = vt + ((size_t)bh * DH_ + d0) * S_ + key0;
#pragma unroll
  for (int i = 0; i < 4; ++i)
    dst[(size_t)(ty + i * 8) * S_ + tx] = t[tx][ty + i * 8];   // VT[d][key]
}

// ---------------------------------------------------------------------------
// Generic bf16 GEMM:  C[M,N] = A[M,K] @ Bt[N,K]^T (+bias, epilogue)
// 256x256 tile, BK=32, 512 thr = 8 waves (2M x 4N), per-wave 128x64 output
// (8x4 frags of 16x16x32, 32 MFMA per K-step per wave).
// Staging: sr = tid>>2 (row 0..127), sl = tid&3; thread loads rows sr and
// 128+sr (64B-contiguous per row, 4 lanes/row). LDS [256 row][4 chunk16B],
// tid-linear dest; slot sl holds global chunk sl^s(row), s=(row^(row>>2))&3.
// Reads use pos = l4 ^ s(row), lane-constant.
// Pipeline (T4+T5): STAGE(next) -> vmcnt(4) [prev tile's loads only; new 4
// stay in flight across the barrier] -> s_barrier -> setprio(1)+MFMA+
// setprio(0) -> s_barrier. LDS total 64KB.
// MFMA operands swapped: acc[i][j] reg r holds m = wm+i*16+(lane&15),
// n = wn+j*16+(lane>>4)*4+r  -> 4 consecutive cols per lane -> vector stores.
// EPI: 0 = bf16 C (+bias), 1 = bf16 C (+bias, fast GELU), 2 = fp32 C (+bias)
// ---------------------------------------------------------------------------
template <int EPI, bool IA, bool IC, bool GUARD>
__global__ __launch_bounds__(512, 2) void gemm_bt(const short* __restrict__ A,
                                                  const short* __restrict__ Bt,
                                                  void* __restrict__ Cp, Ptr3 bias3,
                                                  int N, int K,
                                                  const int* __restrict__ perm,
                                                  const int* __restrict__ meta) {
  const int m0 = blockIdx.x * 256, n0 = blockIdx.y * 256, e = blockIdx.z;
  int rlo = 0, rhi = 0x7fffffff;
  if (GUARD) {
    rlo = meta[3 + e];
    rhi = rlo + meta[e];
    if (m0 >= rhi || m0 + 256 <= rlo) return;
  }
  const short* Bte = Bt + (size_t)e * N * K;
  const float* bias = bias3.p[e];

  __shared__ alignas(16) short As0[8192];    // 16KB each, 64KB total
  __shared__ alignas(16) short As1[8192];
  __shared__ alignas(16) short Bs0[8192];
  __shared__ alignas(16) short Bs1[8192];

  const int tid = threadIdx.x;
  const int lane = tid & 63, wave = tid >> 6;
  const int ln15 = lane & 15, l4 = lane >> 4;
  const int wm = (wave & 1) * 128, wn = (wave >> 1) * 64;
  const int swz = (ln15 ^ (ln15 >> 2)) & 3;  // = s(row) for row = ...+ln15

  // staging geometry: sr = tid>>2 (row 0..127), sl = tid&3 (16B slot);
  // this thread covers rows sr and 128+sr (same swizzle key s0 for both).
  const int sr = tid >> 2, sl = tid & 3;
  const int s0 = (sr ^ (sr >> 2)) & 3;
  const int gch = (sl ^ s0) * 8;             // global chunk this slot holds
  int mr0 = m0 + sr, mr1 = m0 + 128 + sr;
  if (IA) { mr0 = perm[mr0]; mr1 = perm[mr1]; }
  const short* gA0 = A + (size_t)mr0 * K + gch;
  const short* gA1 = A + (size_t)mr1 * K + gch;
  const short* gB0 = Bte + (size_t)(n0 + sr) * K + gch;
  const short* gB1 = Bte + (size_t)(n0 + 128 + sr) * K + gch;
  const int d0 = tid * 8;                    // LDS dst (shorts), rows 0..127
  const int d1 = 4096 + tid * 8;             // rows 128..255

  const f32x4 fz = {0.f, 0.f, 0.f, 0.f};
  f32x4 acc[8][4];
#pragma unroll
  for (int i = 0; i < 8; ++i)
#pragma unroll
    for (int j = 0; j < 4; ++j) acc[i][j] = fz;

#define STAGE(AsP, BsP, k0)                  \
  do {                                       \
    load16_lds(gA0 + (k0), (AsP) + d0);      \
    load16_lds(gA1 + (k0), (AsP) + d1);      \
    load16_lds(gB0 + (k0), (BsP) + d0);      \
    load16_lds(gB1 + (k0), (BsP) + d1);      \
  } while (0)

#define FRAGS_MFMA(AsP, BsP)                                                    \
  do {                                                                          \
    const int pos = (l4 ^ swz) * 8;                                             \
    short8 af[8], bf[4];                                                        \
    _Pragma("unroll") for (int i = 0; i < 8; ++i)                               \
        af[i] = *(const short8*)((AsP) + (wm + i * 16 + ln15) * 32 + pos);      \
    _Pragma("unroll") for (int j = 0; j < 4; ++j)                               \
        bf[j] = *(const short8*)((BsP) + (wn + j * 16 + ln15) * 32 + pos);      \
    __builtin_amdgcn_s_setprio(1);                                              \
    _Pragma("unroll") for (int i = 0; i < 8; ++i)                               \
        _Pragma("unroll") for (int j = 0; j < 4; ++j)                           \
            acc[i][j] = MFMA16(bf[j], af[i], acc[i][j]); /* swapped: C^T */     \
    __builtin_amdgcn_s_setprio(0);                                              \
  } while (0)

#define WAITV(n) asm volatile("s_waitcnt vmcnt(" #n ")" ::: "memory")
#define BAR() __builtin_amdgcn_s_barrier()

  STAGE(As0, Bs0, 0);
  // K/32 is even at every call site (K = 1024 or 4096): tiles pair up.
  int k0 = 32;
  for (; k0 < K - 32; k0 += 64) {
    STAGE(As1, Bs1, k0);        // prefetch odd tile; stays in flight over MFMA
    WAITV(4);                   // previous tile's 4 loads landed
    BAR();
    FRAGS_MFMA(As0, Bs0);
    BAR();                      // no wave still reads As0/Bs0
    STAGE(As0, Bs0, k0 + 32);   // prefetch even tile
    WAITV(4);
    BAR();
    FRAGS_MFMA(As1, Bs1);
    BAR();
  }
  STAGE(As1, Bs1, k0);          // last tile (k0 == K-32 since K/32 even)
  WAITV(4);
  BAR();
  FRAGS_MFMA(As0, Bs0);
  BAR();
  WAITV(0);                     // drain last tile's loads
  BAR();
  FRAGS_MFMA(As1, Bs1);

#undef STAGE
#undef FRAGS_MFMA
#undef WAITV
#undef BAR

  // epilogue: lane holds row = wm+i*16+ln15, cols col0..col0+3
#pragma unroll
  for (int i = 0; i < 8; ++i) {
    const int row = m0 + wm + i * 16 + ln15;
    if (GUARD && (row < rlo || row >= rhi)) continue;
    const int crow = IC ? perm[row] : row;
#pragma unroll
    for (int j = 0; j < 4; ++j) {
      const int col0 = n0 + wn + j * 16 + l4 * 4;
      float4 bv = *(const float4*)(bias + col0);
      float v0 = acc[i][j][0] + bv.x;
      float v1 = acc[i][j][1] + bv.y;
      float v2 = acc[i][j][2] + bv.z;
      float v3 = acc[i][j][3] + bv.w;
      if (EPI == 1) {
        v0 = gelu_fast(v0); v1 = gelu_fast(v1);
        v2 = gelu_fast(v2); v3 = gelu_fast(v3);
      }
      if (EPI == 2) {
        float4 o; o.x = v0; o.y = v1; o.z = v2; o.w = v3;
        *(float4*)((float*)Cp + (size_t)crow * N + col0) = o;
      } else {
        short4 s;
        s.x = f2b(v0); s.y = f2b(v1); s.z = f2b(v2); s.w = f2b(v3);
        *(short4*)((short*)Cp + (size_t)crow * N + col0) = s;
      }
    }
  }
}

// ---------------------------------------------------------------------------
// Flash attention v3: grid (S/128, NH, B), 512 thr = 8 waves x 16 q-rows.
// LDS (48KB): K tile [64 key][16 slots] (XOR-swz), V tile [128 d][8 slots]
// (XOR-swz, from pre-transposed VT), Ps per-wave P scratch. Q region (32KB)
// aliases K+V (consumed into registers before the k-loop).
// K/V staged with coalesced global_load_lds: LDS slot s of row r holds global
// chunk s^(r&7); reads use slot c^(r&7)  (involution, rule #21).
// ---------------------------------------------------------------------------
__global__ __launch_bounds__(512, 4) void flash_attn(const short* __restrict__ qkv,
                                                     const short* __restrict__ vt,
                                                     short* __restrict__ attn) {
  __shared__ alignas(16) short lds[24576];   // 48KB
  short* const Kb = lds;                     // 8192 shorts
  short* const Vb = lds + 8192;              // 8192 shorts
  short* const Ps = lds + 16384;             // 8192 shorts (8 waves x 16q x 64k)

  const int tid = threadIdx.x, lane = tid & 63, wave = tid >> 6;
  const int ln15 = lane & 15, l4 = lane >> 4, ln7 = lane & 7;
  const int q0 = blockIdx.x * 128, h = blockIdx.y, b = blockIdx.z;
  const size_t rs = H3;
  const short* qb = qkv + (size_t)b * S_ * rs + h * DH_;
  const short* kb = qb + H_;
  const short* vtb = vt + (size_t)(b * NH_ + h) * DH_ * S_;

  // ---- prologue: stage Q tile [16 chunk][128 row] into lds[0:16384) ----
#pragma unroll
  for (int it = 0; it < 4; ++it) {
    int idx = it * 512 + tid;                 // 2048 chunks of 16B
    int row = idx & 127, ch = idx >> 7;
    load16_lds(qb + (size_t)(q0 + row) * rs + ch * 8, lds + idx * 8);
  }
  __syncthreads();
  short8 qf[4];
#pragma unroll
  for (int kbi = 0; kbi < 4; ++kbi)
    qf[kbi] = *(const short8*)(lds + ((kbi * 4 + l4) * 128 + wave * 16 + ln15) * 8);
  __syncthreads();   // Q fully in regs before K/V staging overwrites it

  const f32x4 fz = {0.f, 0.f, 0.f, 0.f};
  float mr[4], lr[4];
  f32x4 o[8];
#pragma unroll
  for (int r = 0; r < 4; ++r) { mr[r] = -1e30f; lr[r] = 0.f; }
#pragma unroll
  for (int t = 0; t < 8; ++t) o[t] = fz;

  for (int kt = 0; kt < 32; ++kt) {
    const int key0 = kt * 64;
    // stage K: [64 key][16 slot16B], slot sl holds global d-chunk sl^(key&7)
#pragma unroll
    for (int it = 0; it < 2; ++it) {
      int idx = it * 512 + tid;
      int key = idx >> 4, sl = idx & 15;
      load16_lds(kb + (size_t)(key0 + key) * rs + ((sl ^ (key & 7)) * 8),
                 Kb + idx * 8);
    }
    // stage V: [128 d][8 slot16B], slot sl holds global key-chunk sl^(d&7)
#pragma unroll
    for (int it = 0; it < 2; ++it) {
      int idx = it * 512 + tid;
      int d = idx >> 3, sl = idx & 7;
      load16_lds(vtb + (size_t)d * S_ + key0 + ((sl ^ (d & 7)) * 8),
                 Vb + idx * 8);
    }
    __syncthreads();

    // QK^T: sacc[nt][r] = score[q = wave*16 + l4*4 + r][key = nt*16 + ln15]
    f32x4 sacc[4] = {fz, fz, fz, fz};
#pragma unroll
    for (int nt = 0; nt < 4; ++nt) {
      const int key = nt * 16 + ln15;
#pragma unroll
      for (int kbi = 0; kbi < 4; ++kbi) {
        short8 kf = *(const short8*)(Kb + key * 128 + (((kbi * 4 + l4) ^ ln7) * 8));
        sacc[nt] = MFMA16(qf[kbi], kf, sacc[nt]);
      }
    }
#pragma unroll
    for (int nt = 0; nt < 4; ++nt) sacc[nt] *= 0.08838834764831845f;

    // online softmax with defer-max (skip rescale while max growth <= 8)
    short* myP = Ps + wave * 1024;
#pragma unroll
    for (int r = 0; r < 4; ++r) {
      float mx = fmaxf(fmaxf(sacc[0][r], sacc[1][r]), fmaxf(sacc[2][r], sacc[3][r]));
#pragma unroll
      for (int sh = 8; sh >= 1; sh >>= 1) mx = fmaxf(mx, __shfl_xor(mx, sh, 64));
      if (!__all(mx <= mr[r] + 8.0f)) {
        float mnew = fmaxf(mr[r], mx);
        float alpha = __expf(mr[r] - mnew);
        mr[r] = mnew;
        lr[r] *= alpha;
#pragma unroll
        for (int t = 0; t < 8; ++t) o[t][r] *= alpha;
      }
      float rsum = 0.f;
#pragma unroll
      for (int nt = 0; nt < 4; ++nt) {
        float p = __expf(sacc[nt][r] - mr[r]);
        rsum += p;
        int colc = nt * 16 + ln15;
        myP[((colc >> 3) * 16 + l4 * 4 + r) * 8 + (colc & 7)] = f2b(p);
      }
#pragma unroll
      for (int sh = 8; sh >= 1; sh >>= 1) rsum += __shfl_xor(rsum, sh, 64);
      lr[r] += rsum;
    }

    // PV: o[t] += P[q][k] * V[k][d = t*16 + ln15]
#pragma unroll
    for (int kbi = 0; kbi < 2; ++kbi) {
      short8 pf = *(const short8*)(myP + ((kbi * 4 + l4) * 16 + ln15) * 8);
#pragma unroll
      for (int t = 0; t < 8; ++t) {
        short8 vf = *(const short8*)(Vb + (t * 16 + ln15) * 64 +
                                     (((kbi * 4 + l4) ^ ln7) * 8));
        o[t] = MFMA16(pf, vf, o[t]);
      }
    }
    __syncthreads();
  }

  short* ob = attn + (size_t)b * S_ * H_ + h * DH_;
#pragma unroll
  for (int r = 0; r < 4; ++r) {
    float inv = 1.0f / lr[r];
    int row = q0 + wave * 16 + l4 * 4 + r;
#pragma unroll
    for (int t = 0; t < 8; ++t)
      ob[(size_t)row * H_ + t * 16 + ln15] = f2b(o[t][r] * inv);
  }
}

// ---------------------------------------------------------------------------
__device__ __forceinline__ float block_sum(float v, float* sh, int tid) {
#pragma unroll
  for (int s = 32; s >= 1; s >>= 1) v += __shfl_xor(v, s, 64);
  if ((tid & 63) == 0) sh[tid >> 6] = v;
  __syncthreads();
  float r = sh[0] + sh[1] + sh[2] + sh[3];
  __syncthreads();
  return r;
}

template <bool ABF>
__global__ __launch_bounds__(256) void ln_res(const void* __restrict__ xa,
                                              const float* __restrict__ xb,
                                              const float* __restrict__ g,
                                              const float* __restrict__ bb,
                                              float* __restrict__ of,
                                              short* __restrict__ ob) {
  __shared__ float sh[4];
  int row = blockIdx.x, tid = threadIdx.x;
  size_t base = (size_t)row * H_ + tid * 4;
  float a0, a1, a2, a3;
  if (ABF) {
    short4 a = *(const short4*)((const short*)xa + base);
    a0 = b2f(a.x); a1 = b2f(a.y); a2 = b2f(a.z); a3 = b2f(a.w);
  } else {
    float4 a = *(const float4*)((const float*)xa + base);
    a0 = a.x; a1 = a.y; a2 = a.z; a3 = a.w;
  }
  float4 b = *(const float4*)(xb + base);
  float v0 = a0 + b.x, v1 = a1 + b.y, v2 = a2 + b.z, v3 = a3 + b.w;
  float total = block_sum(v0 + v1 + v2 + v3, sh, tid);
  float mean = total * (1.0f / H_);
  float d0 = v0 - mean, d1 = v1 - mean, d2 = v2 - mean, d3 = v3 - mean;
  float qs = block_sum(d0 * d0 + d1 * d1 + d2 * d2 + d3 * d3, sh, tid);
  float rstd = rsqrtf(qs * (1.0f / H_) + 1e-5f);
  float4 gv = *(const float4*)(g + tid * 4);
  float4 bv = *(const float4*)(bb + tid * 4);
  float r0 = d0 * rstd * gv.x + bv.x;
  float r1 = d1 * rstd * gv.y + bv.y;
  float r2 = d2 * rstd * gv.z + bv.z;
  float r3 = d3 * rstd * gv.w + bv.w;
  if (of) {
    float4 o; o.x = r0; o.y = r1; o.z = r2; o.w = r3;
    *(float4*)(of + base) = o;
  }
  if (ob) {
    short4 s;
    s.x = f2b(r0); s.y = f2b(r1); s.z = f2b(r2); s.w = f2b(r3);
    *(short4*)(ob + base) = s;
  }
}

// ---------------------------------------------------------------------------
__global__ __launch_bounds__(256) void count_experts(const int* __restrict__ mm,
                                                     int* __restrict__ meta) {
  __shared__ int c[3];
  int tid = threadIdx.x;
  if (tid < 3) c[tid] = 0;
  __syncthreads();
  int l0 = 0, l1 = 0, l2 = 0;
  for (int t = tid; t < TOK; t += 256) {
    int e = mm[t];
    l0 += (e == 0); l1 += (e == 1); l2 += (e == 2);
  }
  atomicAdd(&c[0], l0); atomicAdd(&c[1], l1); atomicAdd(&c[2], l2);
  __syncthreads();
  if (tid == 0) {
    meta[0] = c[0]; meta[1] = c[1]; meta[2] = c[2];
    meta[3] = 0;    meta[4] = c[0]; meta[5] = c[0] + c[1];
    meta[6] = 0;    meta[7] = c[0]; meta[8] = c[0] + c[1];
  }
}

__global__ __launch_bounds__(256) void assign_experts(const int* __restrict__ mm,
                                                      int* __restrict__ meta,
                                                      int* __restrict__ perm) {
  int t = blockIdx.x * 256 + threadIdx.x;
  int e = mm[t];
  int lane = threadIdx.x & 63;
  unsigned long long m0 = __ballot(e == 0);
  unsigned long long m1 = __ballot(e == 1);
  unsigned long long m2 = __ballot(e == 2);
  unsigned long long mine = (e == 0) ? m0 : ((e == 1) ? m1 : m2);
  int rank = __popcll(mine & ((1ULL << lane) - 1ULL));
  int leader = __ffsll((unsigned long long)mine) - 1;
  int wb = 0;
  if (lane == leader) wb = atomicAdd(meta + 6 + e, __popcll(mine));
  wb = __shfl(wb, leader, 64);
  perm[wb + rank] = t;
}

// ---------------------------------------------------------------------------
extern "C" void kernel_launch(void* const* d_in, const int* in_sizes, int n_in,
                              void* d_out, int out_size, void* d_ws, size_t ws_size,
                              hipStream_t stream) {
  const float* x    = (const float*)d_in[0];
  const int*   mm   = (const int*)d_in[1];
  const float* Wqkv = (const float*)d_in[3];
  const float* bqkv = (const float*)d_in[4];
  const float* Wout = (const float*)d_in[5];
  const float* bout = (const float*)d_in[6];
  const float* ln1g = (const float*)d_in[7];
  const float* ln1b = (const float*)d_in[8];
  const float* W1[3] = {(const float*)d_in[9],  (const float*)d_in[13], (const float*)d_in[17]};
  const float* b1[3] = {(const float*)d_in[10], (const float*)d_in[14], (const float*)d_in[18]};
  const float* W2[3] = {(const float*)d_in[11], (const float*)d_in[15], (const float*)d_in[19]};
  const float* b2[3] = {(const float*)d_in[12], (const float*)d_in[16], (const float*)d_in[20]};
  const float* ln2g = (const float*)d_in[21];
  const float* ln2b = (const float*)d_in[22];

  char* Wp = (char*)d_ws;
  size_t off = 0;
  auto take = [&](size_t bytes) {
    char* p = Wp + off;
    off += (bytes + 255) & ~(size_t)255;
    return p;
  };
  short* WT = (short*)take((size_t)3 * FF_ * H_ * 2);          // 24 MB
  char* R_A = take((size_t)TOK * H_ * 2);                      // 32 MB
  char* R_Q = take((size_t)TOK * FF_ * 2);                     // 128 MB
  char* R_P = take((size_t)TOK * H_ * 4);                      // 64 MB
  int* PERM = (int*)take((size_t)TOK * 4);
  int* META = (int*)take(256);

  short* XB   = (short*)R_A;
  short* ATTN = (short*)R_A;
  short* X1B  = (short*)R_A;
  short* QKV  = (short*)R_Q;
  short* HBUF = (short*)R_Q;
  float* PROJ = (float*)R_P;
  float* EOUT = (float*)R_P;
  short* VT   = (short*)R_P;   // 32 MB, consumed by flash_attn before PROJ

  dim3 tb(32, 8);

  cvt_bf16<<<(TOK * H_ / 4 + 255) / 256, 256, 0, stream>>>(x, XB, TOK * H_ / 4);

  transpose_cvt<<<dim3(H3 / 32, H_ / 32), tb, 0, stream>>>(Wqkv, WT, H_, H3);

  gemm_bt<0, false, false, false><<<dim3(TOK / 256, H3 / 256, 1), 512, 0, stream>>>(
      XB, WT, QKV, Ptr3{{bqkv, bqkv, bqkv}}, H3, H_, nullptr, nullptr);

  transpose_v<<<dim3(S_ / 32, DH_ / 32, B_ * NH_), tb, 0, stream>>>(QKV, VT);

  flash_attn<<<dim3(S_ / 128, NH_, B_), 512, 0, stream>>>(QKV, VT, ATTN);

  transpose_cvt<<<dim3(H_ / 32, H_ / 32), tb, 0, stream>>>(Wout, WT, H_, H_);

  gemm_bt<2, false, false, false><<<dim3(TOK / 256, H_ / 256, 1), 512, 0, stream>>>(
      ATTN, WT, PROJ, Ptr3{{bout, bout, bout}}, H_, H_, nullptr, nullptr);

  ln_res<false><<<TOK, 256, 0, stream>>>(x, PROJ, ln1g, ln1b, nullptr, X1B);

  count_experts<<<1, 256, 0, stream>>>(mm, META);
  assign_experts<<<TOK / 256, 256, 0, stream>>>(mm, META, PERM);

  for (int e = 0; e < 3; ++e)
    transpose_cvt<<<dim3(FF_ / 32, H_ / 32), tb, 0, stream>>>(
        W1[e], WT + (size_t)e * FF_ * H_, H_, FF_);

  gemm_bt<1, true, false, true><<<dim3(TOK / 256, FF_ / 256, 3), 512, 0, stream>>>(
      X1B, WT, HBUF, Ptr3{{b1[0], b1[1], b1[2]}}, FF_, H_, PERM, META);

  for (int e = 0; e < 3; ++e)
    transpose_cvt<<<dim3(H_ / 32, FF_ / 32), tb, 0, stream>>>(
        W2[e], WT + (size_t)e * H_ * FF_, FF_, H_);

  gemm_bt<2, false, true, true><<<dim3(TOK / 256, H_ / 256, 3), 512, 0, stream>>>(
      HBUF, WT, EOUT, Ptr3{{b2[0], b2[1], b2[2]}}, H_, FF_, PERM, META);

  ln_res<true><<<TOK, 256, 0, stream>>>(X1B, EOUT, ln2g, ln2b, (float*)d_out, nullptr);
}